// Round 1
// baseline (356.937 us; speedup 1.0000x reference)
//
#include <hip/hip_runtime.h>

#define B_ 4
#define H_ 16
#define S_ 1024
#define D_ 64
#define NEGV -1000000000.0f

typedef __bf16 bf16x8 __attribute__((ext_vector_type(8)));
typedef float f32x4 __attribute__((ext_vector_type(4)));

// ---------------- Kernel 1: topic softmax -> topic_probs [B,S,S] fp32 in ws ----------------
__global__ __launch_bounds__(256) void topic_kernel(
    const float* __restrict__ tq, const float* __restrict__ tk,
    const int* __restrict__ mask, float* __restrict__ tp)
{
  int bid = blockIdx.x;            // B*S blocks
  int b = bid >> 10, q = bid & 1023;
  int tid = threadIdx.x;
  __shared__ float s_q[64];
  __shared__ float s_wmax[4], s_wsum[4];
  if (tid < 16) ((float4*)s_q)[tid] = ((const float4*)(tq + ((size_t)b*S_ + q)*D_))[tid];
  int mq = mask[b*S_ + q];
  __syncthreads();
  const float* tkb = tk + (size_t)b*S_*D_;
  float sc[4];
  #pragma unroll
  for (int j = 0; j < 4; ++j) {
    int k = tid + j*256;
    const float4* kr = (const float4*)(tkb + (size_t)k*D_);
    float acc = 0.f;
    #pragma unroll
    for (int t = 0; t < 16; ++t) {
      float4 v = kr[t]; float4 qv = ((float4*)s_q)[t];
      acc += v.x*qv.x + v.y*qv.y + v.z*qv.z + v.w*qv.w;
    }
    sc[j] = (mq && mask[b*S_ + k]) ? acc*0.125f : 1.0f;
  }
  float m = fmaxf(fmaxf(sc[0],sc[1]), fmaxf(sc[2],sc[3]));
  #pragma unroll
  for (int o = 32; o >= 1; o >>= 1) m = fmaxf(m, __shfl_xor(m, o));
  if ((tid & 63) == 0) s_wmax[tid>>6] = m;
  __syncthreads();
  m = fmaxf(fmaxf(s_wmax[0],s_wmax[1]), fmaxf(s_wmax[2],s_wmax[3]));
  float e[4]; float sum = 0.f;
  #pragma unroll
  for (int j = 0; j < 4; ++j) { e[j] = expf(sc[j]-m); sum += e[j]; }
  #pragma unroll
  for (int o = 32; o >= 1; o >>= 1) sum += __shfl_xor(sum, o);
  if ((tid & 63) == 0) s_wsum[tid>>6] = sum;
  __syncthreads();
  sum = s_wsum[0]+s_wsum[1]+s_wsum[2]+s_wsum[3];
  float inv = 1.0f/sum;
  float* tpr = tp + ((size_t)b*S_ + q)*S_;
  #pragma unroll
  for (int j = 0; j < 4; ++j) tpr[tid + j*256] = e[j]*inv;
}

// ---------------- Kernel 2: attention ----------------
// block = 256 threads (4 waves); one block per (b, h, q-tile of 16 rows)
__global__ __launch_bounds__(256) void attn_kernel(
    const float* __restrict__ Q, const float* __restrict__ K,
    const float* __restrict__ V, const int* __restrict__ mask,
    const float* __restrict__ tp, float* __restrict__ out,
    float* __restrict__ pa)
{
  int bid = blockIdx.x;
  int qt = bid & 63;               // S/16 = 64 q-tiles
  int h  = (bid >> 6) & 15;
  int b  = bid >> 10;
  int tid = threadIdx.x;
  int wave = tid >> 6, lane = tid & 63;
  int l15 = lane & 15, lhi = lane >> 4;

  __shared__ __bf16 s_p[16][1040];   // scores then probs (bf16), padded stride (16B-aligned)
  __shared__ __bf16 s_vt[64][264];   // V^T chunk: 64 d x 256 k (+pad)
  __shared__ int s_mk[S_];
  __shared__ int s_mq[16];

  size_t bh = (size_t)b*H_ + h;
  const float* Qb = Q + (bh*S_ + (size_t)qt*16)*D_;
  const float* Kb = K + bh*S_*D_;
  const float* Vb = V + bh*S_*D_;
  const float* tpb = tp + ((size_t)b*S_ + (size_t)qt*16)*S_;  // [16 rows][1024]

  for (int i = tid; i < S_; i += 256) s_mk[i] = mask[b*S_ + i];
  if (tid < 16) s_mq[tid] = mask[b*S_ + qt*16 + tid];

  // Q fragments (A): row = l15, k(d) = dc*32 + lhi*8 + i  (constant across k-tiles)
  bf16x8 qf[2];
  #pragma unroll
  for (int dc = 0; dc < 2; ++dc) {
    const float* p = Qb + (size_t)l15*D_ + dc*32 + lhi*8;
    float4 x = *(const float4*)p;
    float4 y = *(const float4*)(p+4);
    bf16x8 f;
    f[0]=(__bf16)x.x; f[1]=(__bf16)x.y; f[2]=(__bf16)x.z; f[3]=(__bf16)x.w;
    f[4]=(__bf16)y.x; f[5]=(__bf16)y.y; f[6]=(__bf16)y.z; f[7]=(__bf16)y.w;
    qf[dc] = f;
  }
  __syncthreads();

  // ---- QK^T: wave w covers k in [w*256, w*256+256) ----
  for (int kt = 0; kt < 16; ++kt) {
    int kb = wave*256 + kt*16;
    f32x4 acc = {0.f,0.f,0.f,0.f};
    const float* krow = Kb + (size_t)(kb + l15)*D_;
    #pragma unroll
    for (int dc = 0; dc < 2; ++dc) {
      const float* p = krow + dc*32 + lhi*8;
      float4 x = *(const float4*)p;
      float4 y = *(const float4*)(p+4);
      bf16x8 f;
      f[0]=(__bf16)x.x; f[1]=(__bf16)x.y; f[2]=(__bf16)x.z; f[3]=(__bf16)x.w;
      f[4]=(__bf16)y.x; f[5]=(__bf16)y.y; f[6]=(__bf16)y.z; f[7]=(__bf16)y.w;
      acc = __builtin_amdgcn_mfma_f32_16x16x32_bf16(qf[dc], f, acc, 0, 0, 0);
    }
    int kcol = kb + l15;
    int mk = s_mk[kcol];
    #pragma unroll
    for (int i = 0; i < 4; ++i) {
      int row = lhi*4 + i;                 // C/D: row=(lane>>4)*4+i, col=lane&15
      float s = acc[i]*0.125f;
      if (!(s_mq[row] && mk)) s = NEGV;
      s *= tpb[(size_t)row*S_ + kcol];
      s_p[row][kcol] = (__bf16)s;
    }
  }
  __syncthreads();

  // ---- softmax: wave owns rows [wave*4, wave*4+4) ----
  #pragma unroll
  for (int r = 0; r < 4; ++r) {
    int row = wave*4 + r;
    float sv[16];
    float m = -3.4e38f;
    #pragma unroll
    for (int j = 0; j < 16; ++j) {
      sv[j] = (float)s_p[row][lane + j*64];
      m = fmaxf(m, sv[j]);
    }
    #pragma unroll
    for (int o = 32; o >= 1; o >>= 1) m = fmaxf(m, __shfl_xor(m, o));
    float ev[16]; float sum = 0.f;
    #pragma unroll
    for (int j = 0; j < 16; ++j) { ev[j] = expf(sv[j]-m); sum += ev[j]; }
    #pragma unroll
    for (int o = 32; o >= 1; o >>= 1) sum += __shfl_xor(sum, o);
    float inv = 1.0f/sum;
    float* par = pa + (bh*S_ + (size_t)qt*16 + row)*S_;
    #pragma unroll
    for (int j = 0; j < 16; ++j) {
      float pv = ev[j]*inv;
      par[lane + j*64] = pv;               // coalesced fp32 write of p_attn
      s_p[row][lane + j*64] = (__bf16)pv;  // keep P in LDS (bf16) for PV
    }
  }

  // ---- PV: out[16q][64d]; wave w covers d in [w*16, w*16+16) ----
  f32x4 oacc = {0.f,0.f,0.f,0.f};
  for (int kc = 0; kc < 4; ++kc) {
    __syncthreads();                       // P ready / previous chunk consumed
    #pragma unroll
    for (int r = 0; r < 16; ++r) {
      int kk = (tid >> 4) + r*16;
      const float4 v = *(const float4*)(Vb + (size_t)(kc*256 + kk)*D_ + (tid & 15)*4);
      int d0 = (tid & 15)*4;
      s_vt[d0+0][kk] = (__bf16)v.x;
      s_vt[d0+1][kk] = (__bf16)v.y;
      s_vt[d0+2][kk] = (__bf16)v.z;
      s_vt[d0+3][kk] = (__bf16)v.w;
    }
    __syncthreads();
    #pragma unroll
    for (int ks = 0; ks < 8; ++ks) {
      bf16x8 a  = *(const bf16x8*)&s_p[l15][kc*256 + ks*32 + lhi*8];
      bf16x8 bf = *(const bf16x8*)&s_vt[wave*16 + l15][ks*32 + lhi*8];
      oacc = __builtin_amdgcn_mfma_f32_16x16x32_bf16(a, bf, oacc, 0, 0, 0);
    }
  }
  #pragma unroll
  for (int i = 0; i < 4; ++i) {
    int row = lhi*4 + i;
    out[(bh*S_ + (size_t)qt*16 + row)*D_ + wave*16 + l15] = oacc[i];
  }
}

extern "C" void kernel_launch(void* const* d_in, const int* in_sizes, int n_in,
                              void* d_out, int out_size, void* d_ws, size_t ws_size,
                              hipStream_t stream) {
  const float* Q    = (const float*)d_in[0];
  const float* K    = (const float*)d_in[1];
  const float* V    = (const float*)d_in[2];
  const int*   mask = (const int*)d_in[4];
  const float* tq   = (const float*)d_in[5];
  const float* tk   = (const float*)d_in[6];

  float* tp   = (float*)d_ws;                       // [B,S,S] fp32 = 16 MB
  float* outp = (float*)d_out;                      // [B,H,S,D]
  float* pa   = outp + (size_t)B_*H_*S_*D_;         // [B,H,S,S]

  topic_kernel<<<B_*S_, 256, 0, stream>>>(tq, tk, mask, tp);
  attn_kernel<<<B_*H_*(S_/16), 256, 0, stream>>>(Q, K, V, mask, tp, outp, pa);
}

// Round 2
// 190.923 us; speedup vs baseline: 1.8695x; 1.8695x over previous
//
#include <hip/hip_runtime.h>

#define B_ 4
#define H_ 16
#define S_ 1024
#define D_ 64
#define NEGV -1000000000.0f

typedef __bf16 bf16x8 __attribute__((ext_vector_type(8)));
typedef float f32x4 __attribute__((ext_vector_type(4)));

// ---------------- prep: K f32 -> Kb (bf16 [B,H,S,D]), V f32 -> Vt (bf16 [B,H,D,S]) ----------------
__global__ __launch_bounds__(256) void prep_kernel(
    const float* __restrict__ K, const float* __restrict__ V,
    __bf16* __restrict__ Kb, __bf16* __restrict__ Vt)
{
  int bid = blockIdx.x;            // B*H*16 blocks, each a 64-row s-chunk
  int sc = bid & 15;
  int bh = bid >> 4;
  int tid = threadIdx.x;
  __shared__ float s_v[64][65];

  const float* Kc = K + ((size_t)bh*S_ + sc*64)*D_;
  const float* Vc = V + ((size_t)bh*S_ + sc*64)*D_;
  __bf16* Kbc = Kb + ((size_t)bh*S_ + sc*64)*D_;

  // K convert: 64*64 = 4096 elems, 16 per thread
  {
    const float4* src = (const float4*)Kc + tid*4;
    float4 a = src[0], b = src[1], c = src[2], d = src[3];
    bf16x8 o0, o1;
    o0[0]=(__bf16)a.x; o0[1]=(__bf16)a.y; o0[2]=(__bf16)a.z; o0[3]=(__bf16)a.w;
    o0[4]=(__bf16)b.x; o0[5]=(__bf16)b.y; o0[6]=(__bf16)b.z; o0[7]=(__bf16)b.w;
    o1[0]=(__bf16)c.x; o1[1]=(__bf16)c.y; o1[2]=(__bf16)c.z; o1[3]=(__bf16)c.w;
    o1[4]=(__bf16)d.x; o1[5]=(__bf16)d.y; o1[6]=(__bf16)d.z; o1[7]=(__bf16)d.w;
    *(bf16x8*)(Kbc + tid*16)     = o0;
    *(bf16x8*)(Kbc + tid*16 + 8) = o1;
  }
  // stage V chunk [64 s][64 d] into LDS
  for (int i = tid; i < 64*16; i += 256) {
    int r = i >> 4, c4 = i & 15;
    float4 v = ((const float4*)(Vc + (size_t)r*D_))[c4];
    s_v[r][c4*4+0] = v.x; s_v[r][c4*4+1] = v.y;
    s_v[r][c4*4+2] = v.z; s_v[r][c4*4+3] = v.w;
  }
  __syncthreads();
  // write Vt[d][s]: thread -> (d = tid>>2, seg = tid&3), 16 consecutive s
  {
    int d = tid >> 2, seg = tid & 3;
    bf16x8 o0, o1;
    #pragma unroll
    for (int j = 0; j < 8; ++j) o0[j] = (__bf16)s_v[seg*16 + j][d];
    #pragma unroll
    for (int j = 0; j < 8; ++j) o1[j] = (__bf16)s_v[seg*16 + 8 + j][d];
    __bf16* dst = Vt + ((size_t)bh*D_ + d)*S_ + sc*64 + seg*16;
    *(bf16x8*)dst = o0;
    *(bf16x8*)(dst + 8) = o1;
  }
}

// ---------------- topic: MFMA topic scores + softmax -> signed tp [B,S,S] f32 ----------------
// tp > 0: pair-unmasked, value = topic_prob; tp < 0: pair-masked, |tp| = topic_prob
__global__ __launch_bounds__(256) void topic_kernel(
    const float* __restrict__ tq, const float* __restrict__ tk,
    const int* __restrict__ mask, float* __restrict__ tp)
{
  int bid = blockIdx.x;            // B*64 blocks, 16 q-rows each
  int qt = bid & 63, b = bid >> 6;
  int tid = threadIdx.x;
  int wave = tid >> 6, lane = tid & 63;
  int l15 = lane & 15, lhi = lane >> 4;

  __shared__ float s_t[16*1024];   // swizzled: idx = row*1024 + (col ^ ((row&7)<<2))

  // tq fragments (A): row=l15, k(d)=dc*32+lhi*8+i
  bf16x8 qf[2];
  #pragma unroll
  for (int dc = 0; dc < 2; ++dc) {
    const float* p = tq + ((size_t)b*S_ + qt*16 + l15)*D_ + dc*32 + lhi*8;
    float4 x = *(const float4*)p;
    float4 y = *(const float4*)(p+4);
    bf16x8 f;
    f[0]=(__bf16)x.x; f[1]=(__bf16)x.y; f[2]=(__bf16)x.z; f[3]=(__bf16)x.w;
    f[4]=(__bf16)y.x; f[5]=(__bf16)y.y; f[6]=(__bf16)y.z; f[7]=(__bf16)y.w;
    qf[dc] = f;
  }
  int mq[4];
  #pragma unroll
  for (int i = 0; i < 4; ++i) mq[i] = mask[b*S_ + qt*16 + lhi*4 + i];

  for (int kt = 0; kt < 16; ++kt) {
    int kb = wave*256 + kt*16;
    int kcol = kb + l15;
    f32x4 acc = {0.f,0.f,0.f,0.f};
    #pragma unroll
    for (int dc = 0; dc < 2; ++dc) {
      const float* p = tk + ((size_t)b*S_ + kcol)*D_ + dc*32 + lhi*8;
      float4 x = *(const float4*)p;
      float4 y = *(const float4*)(p+4);
      bf16x8 f;
      f[0]=(__bf16)x.x; f[1]=(__bf16)x.y; f[2]=(__bf16)x.z; f[3]=(__bf16)x.w;
      f[4]=(__bf16)y.x; f[5]=(__bf16)y.y; f[6]=(__bf16)y.z; f[7]=(__bf16)y.w;
      acc = __builtin_amdgcn_mfma_f32_16x16x32_bf16(qf[dc], f, acc, 0, 0, 0);
    }
    int mk = mask[b*S_ + kcol];
    #pragma unroll
    for (int i = 0; i < 4; ++i) {
      int row = lhi*4 + i;
      float s = (mq[i] && mk) ? acc[i]*0.125f : 1.0f;
      s_t[row*1024 + (kcol ^ ((row&7)<<2))] = s;
    }
  }
  __syncthreads();

  // softmax: wave owns rows [wave*4, wave*4+4)
  int mkv[16];
  #pragma unroll
  for (int j = 0; j < 16; ++j) mkv[j] = mask[b*S_ + lane + j*64];
  int mqr[4];
  #pragma unroll
  for (int r = 0; r < 4; ++r) mqr[r] = mask[b*S_ + qt*16 + wave*4 + r];

  #pragma unroll
  for (int r = 0; r < 4; ++r) {
    int row = wave*4 + r;
    int swz = (row & 7) << 2;
    float sv[16]; float m = -3.4e38f;
    #pragma unroll
    for (int j = 0; j < 16; ++j) {
      sv[j] = s_t[row*1024 + ((lane + j*64) ^ swz)];
      m = fmaxf(m, sv[j]);
    }
    #pragma unroll
    for (int o = 32; o >= 1; o >>= 1) m = fmaxf(m, __shfl_xor(m, o));
    float ev[16]; float sum = 0.f;
    #pragma unroll
    for (int j = 0; j < 16; ++j) { ev[j] = __expf(sv[j]-m); sum += ev[j]; }
    #pragma unroll
    for (int o = 32; o >= 1; o >>= 1) sum += __shfl_xor(sum, o);
    float inv = 1.0f/sum;
    float* tpr = tp + ((size_t)b*S_ + qt*16 + row)*S_;
    #pragma unroll
    for (int j = 0; j < 16; ++j) {
      float p = ev[j]*inv;
      tpr[lane + j*64] = (mqr[r] && mkv[j]) ? p : -p;
    }
  }
}

// ---------------- attn: QK^T (MFMA) -> mask*topic -> softmax -> PV (MFMA) ----------------
__global__ __launch_bounds__(256) void attn_kernel(
    const float* __restrict__ Q, const __bf16* __restrict__ Kb,
    const __bf16* __restrict__ Vt, const float* __restrict__ tp,
    float* __restrict__ out, float* __restrict__ pa)
{
  // XCD-bijective swizzle: nwg=4096 = 8 XCD * 512; XCD x gets logical [x*512, x*512+512)
  int bid0 = blockIdx.x;
  int bid = (bid0 & 7)*512 + (bid0 >> 3);
  int qt = bid & 63;
  int h  = (bid >> 6) & 15;
  int b  = bid >> 10;
  int tid = threadIdx.x;
  int wave = tid >> 6, lane = tid & 63;
  int l15 = lane & 15, lhi = lane >> 4;

  __shared__ __bf16 s_p[16*1024];  // swizzled: byte = row*2048 + ((col*2) ^ ((row&7)<<4))

  size_t bh = (size_t)b*H_ + h;
  const __bf16* Kbh = Kb + bh*S_*D_;
  const float* tpb = tp + ((size_t)b*S_ + qt*16)*S_;

  // Q fragments
  bf16x8 qf[2];
  #pragma unroll
  for (int dc = 0; dc < 2; ++dc) {
    const float* p = Q + (bh*S_ + qt*16 + l15)*D_ + dc*32 + lhi*8;
    float4 x = *(const float4*)p;
    float4 y = *(const float4*)(p+4);
    bf16x8 f;
    f[0]=(__bf16)x.x; f[1]=(__bf16)x.y; f[2]=(__bf16)x.z; f[3]=(__bf16)x.w;
    f[4]=(__bf16)y.x; f[5]=(__bf16)y.y; f[6]=(__bf16)y.z; f[7]=(__bf16)y.w;
    qf[dc] = f;
  }

  // ---- QK^T: wave w covers k in [w*256, w*256+256) ----
  for (int kt = 0; kt < 16; ++kt) {
    int kb = wave*256 + kt*16;
    int kcol = kb + l15;
    const __bf16* kr = Kbh + (size_t)kcol*D_ + lhi*8;
    bf16x8 k0 = *(const bf16x8*)kr;
    bf16x8 k1 = *(const bf16x8*)(kr + 32);
    f32x4 acc = {0.f,0.f,0.f,0.f};
    acc = __builtin_amdgcn_mfma_f32_16x16x32_bf16(qf[0], k0, acc, 0, 0, 0);
    acc = __builtin_amdgcn_mfma_f32_16x16x32_bf16(qf[1], k1, acc, 0, 0, 0);
    #pragma unroll
    for (int i = 0; i < 4; ++i) {
      int row = lhi*4 + i;
      float t = tpb[(size_t)row*S_ + kcol];
      float at = fabsf(t);
      float s = (t > 0.f ? acc[i]*0.125f : NEGV) * at;
      *(__bf16*)((char*)s_p + row*2048 + (((kcol*2)) ^ ((row&7)<<4))) = (__bf16)s;
    }
  }
  __syncthreads();

  // ---- softmax: wave owns rows [wave*4, wave*4+4) ----
  #pragma unroll
  for (int r = 0; r < 4; ++r) {
    int row = wave*4 + r;
    int swz = (row & 7) << 4;
    float sv[16]; float m = -3.4e38f;
    #pragma unroll
    for (int j = 0; j < 16; ++j) {
      sv[j] = (float)*(const __bf16*)((char*)s_p + row*2048 + (((lane + j*64)*2) ^ swz));
      m = fmaxf(m, sv[j]);
    }
    #pragma unroll
    for (int o = 32; o >= 1; o >>= 1) m = fmaxf(m, __shfl_xor(m, o));
    float ev[16]; float sum = 0.f;
    #pragma unroll
    for (int j = 0; j < 16; ++j) { ev[j] = __expf(sv[j]-m); sum += ev[j]; }
    #pragma unroll
    for (int o = 32; o >= 1; o >>= 1) sum += __shfl_xor(sum, o);
    float inv = 1.0f/sum;
    float* par = pa + (bh*S_ + qt*16 + row)*S_;
    #pragma unroll
    for (int j = 0; j < 16; ++j) {
      float p = ev[j]*inv;
      par[lane + j*64] = p;
      *(__bf16*)((char*)s_p + row*2048 + (((lane + j*64)*2) ^ swz)) = (__bf16)p;
    }
  }
  __syncthreads();

  // ---- PV: wave w covers d in [w*16, w*16+16); V^T read direct from global bf16 ----
  const __bf16* Vh = Vt + (bh*D_ + wave*16 + l15)*S_ + lhi*8;
  f32x4 oacc = {0.f,0.f,0.f,0.f};
  #pragma unroll 8
  for (int ks = 0; ks < 32; ++ks) {
    bf16x8 a  = *(const bf16x8*)((char*)s_p + l15*2048 + (((ks*32 + lhi*8)*2) ^ ((l15&7)<<4)));
    bf16x8 bv = *(const bf16x8*)(Vh + ks*32);
    oacc = __builtin_amdgcn_mfma_f32_16x16x32_bf16(a, bv, oacc, 0, 0, 0);
  }
  #pragma unroll
  for (int i = 0; i < 4; ++i) {
    out[(bh*S_ + qt*16 + lhi*4 + i)*D_ + wave*16 + l15] = oacc[i];
  }
}

extern "C" void kernel_launch(void* const* d_in, const int* in_sizes, int n_in,
                              void* d_out, int out_size, void* d_ws, size_t ws_size,
                              hipStream_t stream) {
  const float* Q    = (const float*)d_in[0];
  const float* K    = (const float*)d_in[1];
  const float* V    = (const float*)d_in[2];
  const int*   mask = (const int*)d_in[4];
  const float* tq   = (const float*)d_in[5];
  const float* tk   = (const float*)d_in[6];

  // ws layout: tp f32 [B,S,S] = 16MB | Kb bf16 [B,H,S,D] = 8MB | Vt bf16 [B,H,D,S] = 8MB
  float*  tp = (float*)d_ws;
  __bf16* Kb = (__bf16*)((char*)d_ws + (size_t)B_*S_*S_*4);
  __bf16* Vt = Kb + (size_t)B_*H_*S_*D_;

  float* outp = (float*)d_out;                      // [B,H,S,D]
  float* pa   = outp + (size_t)B_*H_*S_*D_;         // [B,H,S,S]

  prep_kernel <<<B_*H_*16, 256, 0, stream>>>(K, V, Kb, Vt);
  topic_kernel<<<B_*64,    256, 0, stream>>>(tq, tk, mask, tp);
  attn_kernel <<<B_*H_*64, 256, 0, stream>>>(Q, Kb, Vt, tp, outp, pa);
}